// Round 9
// baseline (74.126 us; speedup 1.0000x reference)
//
#include <hip/hip_runtime.h>

// Problem constants (fixed by setup_inputs)
#define T_STEPS 1000
#define BSZ     512
#define CDIM    64
#define CHUNK   64     // steps per phase (2x R8: halves phase count)
#define NFULL   15     // full chunks 0..14; chunk 15 has TAILN steps
#define TAILN   40     // 1000 - 15*64

// Kernel A: s[row] = sum over C of xs[row, :]   (row = t*B + b)
__global__ __launch_bounds__(256) void rowsum_kernel(const float* __restrict__ xs,
                                                     float* __restrict__ s) {
    int g   = blockIdx.x * 256 + threadIdx.x;
    int row = g >> 4;
    int sub = g & 15;
    float4 v = reinterpret_cast<const float4*>(xs)[row * 16 + sub];
    float t = (v.x + v.y) + (v.z + v.w);
    t += __shfl_xor(t, 1);
    t += __shfl_xor(t, 2);
    t += __shfl_xor(t, 4);
    t += __shfl_xor(t, 8);
    if (sub == 0) s[row] = t;
}

// Quarter-folded Izhikevich step (byte-identical arithmetic to R6-R8):
//   vp = 0.01*v^2 + 2.25*v + (iq - 0.25*u),   iq = 0.25*i + 35
//   up = u + 0.005*(0.2*v - u);  reset: v->-65, u->u_old+6 on vp>30

#define PSTEP(SV, KK)                                                      \
    {                                                                      \
        const float iq = fmaf((SV), Sq, cq);                               \
        float a  = fmaf(-0.25f, u, iq);                                    \
        float vp = fmaf(0.01f, v * v, fmaf(2.25f, v, a));                  \
        float up = fmaf(0.005f, fmaf(0.2f, v, -u), u);                     \
        bool z = vp > 30.0f;                                               \
        v = z ? -65.0f : vp;                                               \
        u = z ? u + 6.0f : up;                                             \
        dst[(KK) * 64] = z ? Gq : 0.0f;                                    \
    }

#define CSTEP(R0, R1, KK)                                                  \
    {                                                                      \
        const float g2q = ((R0) + (R1)) + c3q;                             \
        float a2  = fmaf(-0.25f, u2, g2q);                                 \
        float vp2 = fmaf(0.01f, v2 * v2, fmaf(2.25f, v2, a2));             \
        float up2 = fmaf(0.005f, fmaf(0.2f, v2, -u2), u2);                 \
        bool z2 = vp2 > 30.0f;                                             \
        v2 = z2 ? -65.0f : vp2;                                            \
        u2 = z2 ? u2 + 6.0f : up2;                                         \
        f[KK] = z2 ? 1.0f : 0.0f;                                          \
    }

// Kernel B: 8 blocks x 192 threads (3 waves on 3 SIMDs per CU).
// wave0/wave1 -> producer neuron chains, wave2 -> consumer neuron chain.
// io serves as input (rowsum s, rows >= c+2) and output (spike floats,
// rows <= c-2): writes trail reads by >= 4 chunks, separated by barriers.
// Intentionally NOT __restrict__ (same buffer, both roles).
__global__ __launch_bounds__(192, 1) void recurrence_kernel(
    const float* __restrict__ b1, const float* __restrict__ W2,
    const float* __restrict__ b2, const float* __restrict__ Wg2,
    const float* __restrict__ bg2, const float* __restrict__ W3,
    const float* __restrict__ b3, float* io) {
    const int wave = threadIdx.x >> 6;
    const int lane = threadIdx.x & 63;
    const int b = blockIdx.x * 64 + lane;

    // gbuf[buf][stream][k][lane]: [k][lane] layout -> conflict-free
    __shared__ float gbuf[2][2][CHUNK][64];   // 64 KB

    // Fold tiny linear layers into scalars (all waves; one-time).
    float S20 = 0.f, S21 = 0.f, d0 = 0.f, d1 = 0.f;
#pragma unroll
    for (int j = 0; j < CDIM; ++j) {
        float w0 = W2[j], w1 = W2[CDIM + j], bj = b1[j];
        S20 += w0; S21 += w1;
        d0 += w0 * bj; d1 += w1 * bj;
    }
    const float S20q = 0.25f * S20;
    const float S21q = 0.25f * S21;
    const float c20q = 0.25f * (d0 + b2[0]) + 35.0f;
    const float c21q = 0.25f * (d1 + b2[1]) + 35.0f;
    const float w30 = W3[0], w31 = W3[1];
    const float G0q = 0.25f * (Wg2[0] * w30 + Wg2[2] * w31);
    const float G1q = 0.25f * (Wg2[1] * w30 + Wg2[3] * w31);
    const float c3q = 0.25f * (bg2[0] * w30 + bg2[1] * w31 + b3[0]) + 35.0f;

    if (wave < 2) {
        // -------- producer: neuron `wave` over 1000 steps --------
        const float Sq = wave ? S21q : S20q;
        const float cq = wave ? c21q : c20q;
        const float Gq = wave ? G1q : G0q;
        const int stream = wave;

        float v = -70.f, u = -14.f;
        const float* sp = io + b;

        float A[CHUNK], B[CHUNK];
#pragma unroll
        for (int k = 0; k < CHUNK; ++k) A[k] = sp[k * BSZ];
#pragma unroll
        for (int k = 0; k < CHUNK; ++k) B[k] = sp[(CHUNK + k) * BSZ];

        for (int c = 0; c < NFULL; ++c) {          // compute full chunk c
            float* dst = &gbuf[c & 1][stream][0][lane];
#pragma unroll
            for (int k = 0; k < CHUNK; ++k) PSTEP(A[k], k)
            __syncthreads();
            // rotate A <- B (B is complete: prior loads drained at the barrier)
#pragma unroll
            for (int k = 0; k < CHUNK; ++k) A[k] = B[k];
            // issue next prefetch at the TOP of the phase: the whole next
            // compute covers its latency before the pre-barrier vmcnt drain
            if (c + 2 < NFULL) {
                const int base = (c + 2) * CHUNK;
#pragma unroll
                for (int k = 0; k < CHUNK; ++k) B[k] = sp[(base + k) * BSZ];
            } else if (c + 2 == NFULL) {           // tail chunk 15: 40 steps
#pragma unroll
                for (int k = 0; k < TAILN; ++k) B[k] = sp[(NFULL * CHUNK + k) * BSZ];
            }
        }
        // tail chunk 15 from A
        {
            float* dst = &gbuf[NFULL & 1][stream][0][lane];
#pragma unroll
            for (int k = 0; k < TAILN; ++k) PSTEP(A[k], k)
            __syncthreads();
        }
        __syncthreads();   // consumer drains chunk 15
    } else {
        // -------- consumer: neuron 2 over 1000 steps --------
        float v2 = -70.f, u2 = -14.f;
        float f[CHUNK];
        float* op = io + b;
        __syncthreads();   // chunk 0 now in LDS
        for (int c = 0; c < NFULL; ++c) {
            // store PREVIOUS chunk's spikes first: compute covers the acks
            if (c > 0) {
                const int base = (c - 1) * CHUNK;
#pragma unroll
                for (int k = 0; k < CHUNK; ++k) op[(base + k) * BSZ] = f[k];
            }
            const float* src = &gbuf[c & 1][0][0][lane];
            float r0[CHUNK], r1[CHUNK];
#pragma unroll
            for (int k = 0; k < CHUNK; ++k) r0[k] = src[k * 64];
#pragma unroll
            for (int k = 0; k < CHUNK; ++k) r1[k] = src[CHUNK * 64 + k * 64];
#pragma unroll
            for (int k = 0; k < CHUNK; ++k) CSTEP(r0[k], r1[k], k)
            __syncthreads();
        }
        // tail chunk 15
        {
            const int base = (NFULL - 1) * CHUNK;
#pragma unroll
            for (int k = 0; k < CHUNK; ++k) op[(base + k) * BSZ] = f[k];
            const float* src = &gbuf[NFULL & 1][0][0][lane];
            float r0[TAILN], r1[TAILN];
#pragma unroll
            for (int k = 0; k < TAILN; ++k) r0[k] = src[k * 64];
#pragma unroll
            for (int k = 0; k < TAILN; ++k) r1[k] = src[CHUNK * 64 + k * 64];
#pragma unroll
            for (int k = 0; k < TAILN; ++k) CSTEP(r0[k], r1[k], k)
            __syncthreads();
#pragma unroll
            for (int k = 0; k < TAILN; ++k) op[(NFULL * CHUNK + k) * BSZ] = f[k];
        }
    }
}

extern "C" void kernel_launch(void* const* d_in, const int* in_sizes, int n_in,
                              void* d_out, int out_size, void* d_ws, size_t ws_size,
                              hipStream_t stream) {
    const float* xs  = (const float*)d_in[0];
    const float* b1  = (const float*)d_in[2];
    const float* W2  = (const float*)d_in[3];
    const float* b2  = (const float*)d_in[4];
    const float* Wg2 = (const float*)d_in[5];
    const float* bg2 = (const float*)d_in[6];
    const float* W3  = (const float*)d_in[7];
    const float* b3  = (const float*)d_in[8];
    float* out = (float*)d_out;

    const int rows = T_STEPS * BSZ;                 // 512000
    const int blocksA = rows * 16 / 256;            // 32000
    rowsum_kernel<<<blocksA, 256, 0, stream>>>(xs, out);
    recurrence_kernel<<<8, 192, 0, stream>>>(b1, W2, b2, Wg2, bg2, W3, b3, out);
}